// Round 6
// baseline (346.056 us; speedup 1.0000x reference)
//
#include <hip/hip_runtime.h>

// Problem constants
#define B_    4096
#define T_    32
#define OUT_  8
#define BTILE 32
#define NBLK  (B_ / BTILE)   // 128 main-kernel blocks

typedef _Float16 f16;
typedef _Float16 f16x4 __attribute__((ext_vector_type(4)));
typedef _Float16 f16x8 __attribute__((ext_vector_type(8)));
typedef float    f32x4 __attribute__((ext_vector_type(4)));

#define GPTR(p) ((const __attribute__((address_space(1))) void*)(p))
#define LPTR(p) ((__attribute__((address_space(3))) void*)(p))

// ---- workspace layout (bytes). Total ~24.4 MB ----
// [0, 8448): f32 weights (WA 1024, WO 1024, biasA 16 @f32idx 2048, biasB 16 @f32idx 2112)
#define WS_AENC 16384u                    // [B*T][16] f16 = 4 MB
#define WS_OENC (WS_AENC + 4194304u)      // 4 MB
#define WS_H    (WS_OENC + 4194304u)      // f16 relaid H: 16 MB + 64 KB pad
// H as 512 sub-slabs of 32 KB: sub-slab (t, q) holds p-pair (2q, 2q+1).
// granule (1 KB) at sub-slab byte (pl*16 + s*2 + nf)*1024 ; granule byte lane*16,
// slot h*4+r = Ht[p=2q+pl][j=2s+h][kk=g4*4+r][l=nf*16+m16] * (1/8)

// ------------------- prep 1: fuse encoder weights -------------------
__global__ void k_fuse_w(const float* __restrict__ Wa0, const float* __restrict__ ba0,
                         const float* __restrict__ Wa1, const float* __restrict__ ba1,
                         const float* __restrict__ Wo0, const float* __restrict__ bo0,
                         const float* __restrict__ Wo1, const float* __restrict__ bo1,
                         float* __restrict__ ws) {
  const int tid = threadIdx.x;  // 256 threads, 1 block
  for (int idx = tid; idx < 1024; idx += 256) {
    const int d = idx >> 4, j = idx & 15;
    float s = 0.f, s2 = 0.f;
    for (int h = 0; h < 128; ++h) {
      s  += Wa0[d * 128 + h] * Wa1[h * 16 + j];
      s2 += Wo0[d * 128 + h] * Wo1[h * 16 + j];
    }
    ws[idx] = s;
    ws[1024 + idx] = s2;
  }
  if (tid < 16) {
    float s = 0.f, s2 = 0.f;
    for (int h = 0; h < 128; ++h) {
      s  += ba0[h] * Wa1[h * 16 + tid];
      s2 += bo0[h] * Wo1[h * 16 + tid];
    }
    ws[2048 + tid] = s + ba1[tid];
    ws[2112 + tid] = s2 + bo1[tid];
  }
}

// ------------------- prep 2: MFMA encoder (f16 in, f32 acc) -------------------
__global__ void k_encode(const float* __restrict__ action, const float* __restrict__ obs,
                         const float* __restrict__ ws,
                         f16* __restrict__ aenc, f16* __restrict__ oenc) {
  const int tid = threadIdx.x;
  const int lane = tid & 63;
  const int v = tid >> 6;
  const int m16 = lane & 15, g4 = lane >> 4;
  const int bt0 = blockIdx.x * 64 + v * 16;

  f16x8 wbA[2], wbB[2];
  #pragma unroll
  for (int ks = 0; ks < 2; ++ks)
    #pragma unroll
    for (int h = 0; h < 2; ++h)
      #pragma unroll
      for (int r = 0; r < 4; ++r) {
        const int d = ks * 32 + h * 16 + g4 * 4 + r;
        wbA[ks][h * 4 + r] = (f16)ws[d * 16 + m16];
        wbB[ks][h * 4 + r] = (f16)ws[1024 + d * 16 + m16];
      }
  const float biasA = ws[2048 + m16], biasB = ws[2112 + m16];
  f32x4 accA = {biasA, biasA, biasA, biasA};
  f32x4 accB = {biasB, biasB, biasB, biasB};

  const float* ar = action + (size_t)(bt0 + m16) * 64;
  const float* br = obs    + (size_t)(bt0 + m16) * 64;
  #pragma unroll
  for (int ks = 0; ks < 2; ++ks) {
    f16x8 aa, oo;
    #pragma unroll
    for (int h = 0; h < 2; ++h) {
      const f32x4 a4 = *(const f32x4*)(ar + ks * 32 + h * 16 + g4 * 4);
      const f32x4 o4 = *(const f32x4*)(br + ks * 32 + h * 16 + g4 * 4);
      #pragma unroll
      for (int r = 0; r < 4; ++r) { aa[h * 4 + r] = (f16)a4[r]; oo[h * 4 + r] = (f16)o4[r]; }
    }
    accA = __builtin_amdgcn_mfma_f32_16x16x32_f16(aa, wbA[ks], accA, 0, 0, 0);
    accB = __builtin_amdgcn_mfma_f32_16x16x32_f16(oo, wbB[ks], accB, 0, 0, 0);
  }
  #pragma unroll
  for (int r = 0; r < 4; ++r) {
    aenc[(size_t)(bt0 + g4 * 4 + r) * 16 + m16] = (f16)accA[r];
    oenc[(size_t)(bt0 + g4 * 4 + r) * 16 + m16] = (f16)accB[r];
  }
}

// ------------------- prep 3: relayout H -> f16 sub-slabs, scaled by 1/8 -------------------
__global__ void k_hprep(const float* __restrict__ Hf, const float* __restrict__ Hm,
                        const float* __restrict__ Hl, f16* __restrict__ hdst) {
  const int x = blockIdx.x * 256 + threadIdx.x;     // < 1048576
  const int lane = x & 63;
  const int gid = x >> 6;                           // 16384 granules
  const int nf = gid & 1, s = (gid >> 1) & 7, pl = (gid >> 4) & 1;
  const int q = (gid >> 5) & 15, t = gid >> 9;
  const int p = q * 2 + pl;
  const int m16 = lane & 15, g4 = lane >> 4;
  const int l = nf * 16 + m16;
  f16x8 gout;
  #pragma unroll
  for (int h = 0; h < 2; ++h) {
    const int j = 2 * s + h;
    #pragma unroll
    for (int r = 0; r < 4; ++r) {
      const int kk = g4 * 4 + r;
      float vsrc;
      if (t == 0)       vsrc = (p == 0) ? Hf[(j * 16 + kk) * 32 + l] : 0.f;
      else if (t == 31) vsrc = (l < 8) ? Hl[((p * 16 + j) * 16 + kk) * 8 + l] : 0.f;
      else              vsrc = Hm[((((size_t)(t - 1) * 32 + p) * 16 + j) * 16 + kk) * 32 + l];
      gout[h * 4 + r] = (f16)(vsrc * 0.125f);
    }
  }
  *(f16x8*)((char*)hdst + (size_t)x * 16) = gout;
}

// ------------------- main fused kernel -------------------
// 128 blocks x 512 threads (8 waves). T3+T4: global_load_lds into a 4-deep 32KB
// staging ring, counted vmcnt(8) (never 0), single raw s_barrier per phase.
// Wave w = (nf = w>>2, sq = w&3); per phase: 4 ds_read_b128, 8 MFMAs, acc = 2 f32x4.
// Phase sequence pc = 0..496: Q(pc) = pc ? pc+15 : 0  (t=0 compressed to 1 phase).
__launch_bounds__(512)
__global__ void k_main(const f16* __restrict__ aenc, const f16* __restrict__ oenc,
                       const char* __restrict__ hws, float* __restrict__ out) {
  __shared__ __align__(16) char sbuf[4][32768];     // 128 KB staging ring
  __shared__ float cpart[8][2][16][20];             // 20 KB [wave][mf][l][b], pad 20
  __shared__ float cfull[32][33];                   // 4.2 KB [p][b]

  const int tid  = threadIdx.x;
  const int lane = tid & 63;
  const int w    = tid >> 6;       // 0..7
  const int m16  = lane & 15;
  const int g4   = lane >> 4;      // 0..3
  const int nf   = w >> 2;         // 0..1
  const int sq   = w & 3;          // 0..3
  const int b0   = blockIdx.x * BTILE;

  // init chain state: c[p][b] = (p == 0)
  for (int k2 = tid; k2 < 1024; k2 += 512)
    cfull[k2 >> 5][k2 & 31] = ((k2 >> 5) == 0) ? 1.f : 0.f;
  asm volatile("s_waitcnt lgkmcnt(0)" ::: "memory");

#define STAGE(PCX) do {                                                        \
    const int Qs_ = (PCX) ? (PCX) + 15 : 0;                                    \
    const size_t sb_ = (size_t)Qs_ * 32768 + (size_t)w * 4096 + (size_t)lane * 16; \
    char* db_ = &sbuf[(PCX) & 3][w * 4096];                                    \
    _Pragma("unroll")                                                          \
    for (int i_ = 0; i_ < 4; ++i_)                                             \
      __builtin_amdgcn_global_load_lds(GPTR(hws + sb_ + i_ * 1024),            \
                                       LPTR(db_ + i_ * 1024), 16, 0, 0);       \
  } while (0)

  // prologue: stage phases 0 and 1
  STAGE(0);
  STAGE(1);

  // enc regs for t=0: per-lane a (its 4 j's = 4sq..4sq+3) and o (its 4 kk's) per mf
  f16x4 av0 = *(const f16x4*)(aenc + ((size_t)(b0 + m16) * T_ + 0) * 16 + 4 * sq);
  f16x4 av1 = *(const f16x4*)(aenc + ((size_t)(b0 + 16 + m16) * T_ + 0) * 16 + 4 * sq);
  f16x4 ov0 = *(const f16x4*)(oenc + ((size_t)(b0 + m16) * T_ + 0) * 16 + g4 * 4);
  f16x4 ov1 = *(const f16x4*)(oenc + ((size_t)(b0 + 16 + m16) * T_ + 0) * 16 + g4 * 4);

  int pc = 0;
  #pragma clang loop unroll(disable)
  for (int t = 0; t < T_; ++t) {
    const int nq = (t == 0) ? 1 : 16;
    f32x4 acc0 = {0.f, 0.f, 0.f, 0.f};   // mf = 0 quadrant (its nf)
    f32x4 acc1 = {0.f, 0.f, 0.f, 0.f};   // mf = 1 quadrant

    for (int qq = 0; qq < nq; ++qq, ++pc) {
      const int Q = pc ? pc + 15 : 0;
      STAGE(pc + 2);                                  // pc+2 <= 498 -> pad slabs 512/513
      asm volatile("s_waitcnt vmcnt(8)" ::: "memory"); // keep 2 sub-slabs in flight
      __builtin_amdgcn_s_barrier();

      const int qi = Q & 15;                          // p-pair index within t
      const char* gb = &sbuf[pc & 3][0];
      const f16 c00 = (f16)cfull[2 * qi][m16];
      const f16 c01 = (f16)cfull[2 * qi][16 + m16];
      const f16 c10 = (f16)cfull[2 * qi + 1][m16];
      const f16 c11 = (f16)cfull[2 * qi + 1][16 + m16];

      #pragma unroll
      for (int pl = 0; pl < 2; ++pl) {
        const f16 ca = pl ? c10 : c00;   // c for (p, b = m16)      -> mf0 rows
        const f16 cb = pl ? c11 : c01;   // c for (p, b = 16+m16)   -> mf1 rows
        #pragma unroll
        for (int ss = 0; ss < 2; ++ss) {
          const int sloc = sq * 2 + ss;
          const f16x8 bf = *(const f16x8*)(gb + (pl * 16 + sloc * 2 + nf) * 1024 + lane * 16);
          const f16 a00 = ca * av0[2 * ss], a01 = ca * av0[2 * ss + 1];
          const f16 a10 = cb * av1[2 * ss], a11 = cb * av1[2 * ss + 1];
          f16x8 af0, af1;
          #pragma unroll
          for (int r = 0; r < 4; ++r) {
            af0[r] = a00 * ov0[r]; af0[4 + r] = a01 * ov0[r];
            af1[r] = a10 * ov1[r]; af1[4 + r] = a11 * ov1[r];
          }
          acc0 = __builtin_amdgcn_mfma_f32_16x16x32_f16(af0, bf, acc0, 0, 0, 0);
          acc1 = __builtin_amdgcn_mfma_f32_16x16x32_f16(af1, bf, acc1, 0, 0, 0);
        }
      }
    }

    // ---- chain phase: cross-wave reduce (raw barriers; stage loads stay in flight) ----
    // D: col = m16 (l within nf), rows = mf*16 + g4*4 + r
    *(f32x4*)&cpart[w][0][m16][g4 * 4] = acc0;
    *(f32x4*)&cpart[w][1][m16][g4 * 4] = acc1;

    // preload enc for t+1 (VMEM; overlaps the reduce)
    const int tnn = (t < 31) ? t + 1 : 31;
    av0 = *(const f16x4*)(aenc + ((size_t)(b0 + m16) * T_ + tnn) * 16 + 4 * sq);
    av1 = *(const f16x4*)(aenc + ((size_t)(b0 + 16 + m16) * T_ + tnn) * 16 + 4 * sq);
    ov0 = *(const f16x4*)(oenc + ((size_t)(b0 + m16) * T_ + tnn) * 16 + g4 * 4);
    ov1 = *(const f16x4*)(oenc + ((size_t)(b0 + 16 + m16) * T_ + tnn) * 16 + g4 * 4);

    asm volatile("s_waitcnt lgkmcnt(0)" ::: "memory");
    __builtin_amdgcn_s_barrier();
    #pragma unroll
    for (int rep = 0; rep < 2; ++rep) {
      const int e = tid + rep * 512;
      const int bb = e & 31, L = e >> 5;
      const int mfi = bb >> 4, row = bb & 15, nfi = L >> 4, col = L & 15;
      const float ssum = cpart[nfi * 4 + 0][mfi][col][row] + cpart[nfi * 4 + 1][mfi][col][row]
                       + cpart[nfi * 4 + 2][mfi][col][row] + cpart[nfi * 4 + 3][mfi][col][row];
      if (t < 31) cfull[L][bb] = ssum;
      else if (L < 8) out[(size_t)(b0 + bb) * 8 + L] = ssum * 0x1p96f;  // undo 8^-32 scaling
    }
    asm volatile("s_waitcnt lgkmcnt(0)" ::: "memory");
    __builtin_amdgcn_s_barrier();
  }
  // drain outstanding DMA before LDS dealloc
  asm volatile("s_waitcnt vmcnt(0)" ::: "memory");
#undef STAGE
}

extern "C" void kernel_launch(void* const* d_in, const int* in_sizes, int n_in,
                              void* d_out, int out_size, void* d_ws, size_t ws_size,
                              hipStream_t stream) {
  (void)in_sizes; (void)n_in; (void)out_size; (void)ws_size;
  const float* action = (const float*)d_in[0];
  const float* obs    = (const float*)d_in[1];
  const float* Wa0 = (const float*)d_in[2];
  const float* ba0 = (const float*)d_in[3];
  const float* Wa1 = (const float*)d_in[4];
  const float* ba1 = (const float*)d_in[5];
  const float* Wo0 = (const float*)d_in[6];
  const float* bo0 = (const float*)d_in[7];
  const float* Wo1 = (const float*)d_in[8];
  const float* bo1 = (const float*)d_in[9];
  const float* Hf  = (const float*)d_in[10];
  const float* Hm  = (const float*)d_in[11];
  const float* Hl  = (const float*)d_in[12];
  char*  ws  = (char*)d_ws;
  float* out = (float*)d_out;

  k_fuse_w<<<1, 256, 0, stream>>>(Wa0, ba0, Wa1, ba1, Wo0, bo0, Wo1, bo1, (float*)ws);
  k_encode<<<(B_ * T_) / 64, 256, 0, stream>>>(action, obs, (const float*)ws,
                                               (f16*)(ws + WS_AENC), (f16*)(ws + WS_OENC));
  k_hprep<<<4096, 256, 0, stream>>>(Hf, Hm, Hl, (f16*)(ws + WS_H));
  k_main<<<NBLK, 512, 0, stream>>>((const f16*)(ws + WS_AENC), (const f16*)(ws + WS_OENC),
                                   (const char*)(ws + WS_H), out);
}